// Round 2
// baseline (285.053 us; speedup 1.0000x reference)
//
#include <hip/hip_runtime.h>

// BLAMem: truncated tensor-algebra (depth 4, C=8) log-signature memory.
// Round-9: SINGLE fused kernel (was 5 dispatches). Evidence: removing ~30% of the
// pipeline's VALU work in round-8 moved total only 127->125us => per-dispatch
// overhead/drain dominates, not work. All 5 stages now run in one 256-block kernel
// with manual device-scope grid barriers (117KB LDS => exactly 1 block/CU => all 256
// blocks co-resident; barrier cannot deadlock). Chunk snapshots stay resident in LDS
// across phases (kills the 19.2MB S write + 19.2MB S read of round-8).
// Carried lessons: NO atomics for reductions; row-addressed LDS padded to stride 9;
// all FP summation orders bit-identical to the verified round-0/1 kernels.

#define MEM   4680   // 8 + 64 + 512 + 4096 (unpadded global layout)
#define NG    32     // groups per batch
#define TLEN  2048
#define NBLK  256

// Padded LDS signature layout: L1 [0,8), L2 [8,72), L3 rows (i*8+j)*9+k at 72 (576),
// L4 rows ijk*9+l at 648 (4608). Total 5256 floats.
#define P3OFF 72
#define P4OFF 648
#define SIGSZ 5256

// Device-scope grid barrier. Generation-based: cnt must start 0 (memset before
// launch); gen may start at any value (monotonic). Leader-only atomics; __syncthreads
// drains each thread's memory ops (vmcnt(0) before s_barrier), leader __threadfence
// (agent scope) writes back / invalidates the CU-shared caches for the whole block.
__device__ __forceinline__ void grid_barrier(unsigned* cnt, unsigned* gen) {
    __syncthreads();
    if (threadIdx.x == 0) {
        __threadfence();
        unsigned g = __hip_atomic_load(gen, __ATOMIC_RELAXED, __HIP_MEMORY_SCOPE_AGENT);
        unsigned old = __hip_atomic_fetch_add(cnt, 1u, __ATOMIC_ACQ_REL, __HIP_MEMORY_SCOPE_AGENT);
        if (old == NBLK - 1u) {
            __hip_atomic_store(cnt, 0u, __ATOMIC_RELAXED, __HIP_MEMORY_SCOPE_AGENT);
            __hip_atomic_store(gen, g + 1u, __ATOMIC_RELEASE, __HIP_MEMORY_SCOPE_AGENT);
        } else {
            while (__hip_atomic_load(gen, __ATOMIC_ACQUIRE, __HIP_MEMORY_SCOPE_AGENT) == g) {
                __builtin_amdgcn_s_sleep(1);
            }
        }
        __threadfence();
    }
    __syncthreads();
}

__global__ __launch_bounds__(256) void fused_kernel(
    const float* __restrict__ x,  const float* __restrict__ W1,
    const float* __restrict__ b1, const float* __restrict__ W2,
    const float* __restrict__ b2, float* __restrict__ outp,
    float* __restrict__ T, float* __restrict__ P,
    float* __restrict__ partial, float* __restrict__ hpart,
    unsigned* __restrict__ bar)
{
    const int bid = blockIdx.x;
    const int tid = threadIdx.x;
    const int b = bid >> 5, g = bid & 31;

    // Persistent across phases (block owns one CU): 4 padded chunk snapshots.
    __shared__ __attribute__((aligned(16))) float sSnap[4][SIGSZ];   // 84.1 KB
    __shared__ __attribute__((aligned(16))) float sInc[512];
    __shared__ __attribute__((aligned(16))) float U[648];   // loc3 576 | loc2 64 | loc1 8
    __shared__ __attribute__((aligned(16))) float sR[648];
    // scan phase
    __shared__ float st1[NG][8];
    __shared__ float st2[NG][64];
    __shared__ float st3[NG][32];
    __shared__ float sp1[NG][8];
    __shared__ float sp2[NG][64];
    __shared__ float sp3[NG][32];
    // gemv / final
    __shared__ float spg[8][32];
    __shared__ float sRed[256];

    const int i1 = tid >> 6, j1 = (tid >> 3) & 7, k1 = tid & 7;
    const int row1 = tid >> 3, row2 = row1 + 32;
    const int jk = tid & 63;
    const int pos2 = tid + 256, i2 = pos2 >> 6;

    float* loc3 = U;
    float* loc2 = U + 576;
    float* loc1 = U + 640;

    // ---------------- phase 1: per-group Chen fold, snapshots kept in LDS -------
    for (int e = tid; e < 512; e += 256) {
        int s = e >> 3, c = e & 7;
        int t = g * 64 + s;
        float v;
        if (c < 7) {
            float cur  = x[(b * TLEN + t) * 7 + c];
            float prev = (t > 0) ? x[(b * TLEN + t - 1) * 7 + c] : 0.f;
            v = cur - prev;
        } else v = (t > 0) ? (1.f / 2047.f) : 0.f;
        sInc[e] = v;
    }
    __syncthreads();

    for (int c = 0; c < 4; ++c) {
        const float* dch = &sInc[c * 128];
        float p1a = 0.f, l2a = 0.f, l3a = 0.f, p1b = 0.f, l2b = 0.f, l3b = 0.f;
        float Sa[8], Sb[8];
#pragma unroll
        for (int l = 0; l < 8; l++) { Sa[l] = 0.f; Sb[l] = 0.f; }
#pragma unroll
        for (int t = 0; t < 16; t++) {
            const float* dr = dch + t * 8;
            float di1 = dr[i1], di2 = dr[i2], dj = dr[j1], dk = dr[k1];
            float ga = l3a + dk * (l2a * 0.5f + dj * (p1a * (1.f/6.f) + di1 * (1.f/24.f)));
            float gb = l3b + dk * (l2b * 0.5f + dj * (p1b * (1.f/6.f) + di2 * (1.f/24.f)));
#pragma unroll
            for (int l = 0; l < 8; l++) { float dv = dr[l]; Sa[l] += ga * dv; Sb[l] += gb * dv; }
            l3a += dk * (l2a + dj * (p1a * 0.5f + di1 * (1.f/6.f)));
            l3b += dk * (l2b + dj * (p1b * 0.5f + di2 * (1.f/6.f)));
            l2a += (p1a + di1 * 0.5f) * dj;
            l2b += (p1b + di2 * 0.5f) * dj;
            p1a += di1; p1b += di2;
        }
        loc3[row1 * 9 + k1] = l3a;
        loc3[row2 * 9 + k1] = l3b;
        if (k1 == 0) { loc2[row1] = l2a; loc2[row2] = l2b; }
        if (jk == 0) { loc1[i1] = p1a; loc1[i2] = p1b; }
        __syncthreads();

        float* dst = sSnap[c];
        const float* l3p = &loc3[jk * 9];
        const float* l2p = &loc2[k1 * 8];
        if (c == 0) {
            // prev == 0: snapshot = chunk-local sig (bit-identical to merging with 0)
#pragma unroll
            for (int l = 0; l < 8; l++) { dst[P4OFF + tid * 9 + l] = Sa[l]; dst[P4OFF + pos2 * 9 + l] = Sb[l]; }
            dst[P3OFF + row1 * 9 + k1] = l3a;
            dst[P3OFF + row2 * 9 + k1] = l3b;
            if (tid < 64) dst[8 + tid] = loc2[tid];
            if (tid < 8)  dst[tid] = loc1[tid];
        } else {
            const float* prv = sSnap[c - 1];
            float a1 = prv[i1], a2 = prv[8 + row1], a3 = prv[P3OFF + row1 * 9 + k1];
            float c1_ = prv[i2], c2_ = prv[8 + row2], c3_ = prv[P3OFF + row2 * 9 + k1];
#pragma unroll
            for (int l = 0; l < 8; l++) {
                float v3 = l3p[l], v2 = l2p[l], v1 = loc1[l];
                dst[P4OFF + tid * 9 + l]  = prv[P4OFF + tid * 9 + l]  + Sa[l] + a1 * v3 + a2 * v2 + a3 * v1;
                dst[P4OFF + pos2 * 9 + l] = prv[P4OFF + pos2 * 9 + l] + Sb[l] + c1_ * v3 + c2_ * v2 + c3_ * v1;
            }
            dst[P3OFF + row1 * 9 + k1] = a3 + l3a + a1 * loc2[jk] + a2 * loc1[k1];
            dst[P3OFF + row2 * 9 + k1] = c3_ + l3b + c1_ * loc2[jk] + c2_ * loc1[k1];
            if (tid < 64) dst[8 + tid] = prv[8 + tid] + loc2[tid] + prv[tid >> 3] * loc1[tid & 7];
            if (tid < 8)  dst[tid] = prv[tid] + loc1[tid];
        }
        __syncthreads();
    }

    // write group totals (snapshot 3) compact for the scan
    {
        const float* s3 = sSnap[3];
        float* Tr = T + (size_t)bid * MEM;
        for (int m4 = tid * 4; m4 < MEM; m4 += 1024) {
            float4 v;
            if (m4 < 72) {
                v = make_float4(s3[m4], s3[m4 + 1], s3[m4 + 2], s3[m4 + 3]);
            } else if (m4 < 584) {
                int e = m4 - 72; const float* p0 = &s3[P3OFF + (e >> 3) * 9 + (e & 7)];
                v = make_float4(p0[0], p0[1], p0[2], p0[3]);
            } else {
                int e = m4 - 584; const float* p0 = &s3[P4OFF + (e >> 3) * 9 + (e & 7)];
                v = make_float4(p0[0], p0[1], p0[2], p0[3]);
            }
            *(float4*)(Tr + m4) = v;
        }
    }

    grid_barrier(bar, bar + 1);

    // ---------------- phase 2: cross-group cascade scan (blocks 0..127) ---------
    if (bid < 128) {
        const int b2 = bid >> 4, s = bid & 15;
        const int bBase = b2 * NG;
        const int jkl   = ((s & 1) << 8) | tid;
        const int m4idx = s * 256 + tid;

        float rL4[NG], rL3[NG];
#pragma unroll
        for (int gg = 0; gg < NG; gg++) {
            const float* Trow = T + (size_t)(bBase + gg) * MEM;
            rL4[gg] = Trow[584 + m4idx];
            rL3[gg] = Trow[72 + jkl];
        }
        {
            int gg = tid >> 3, i = tid & 7;
            st1[gg][i] = T[(size_t)(bBase + gg) * MEM + i];
        }
        for (int m = tid * 4; m < NG * 64; m += 1024) {
            int gg = m >> 6, e = m & 63;
            *(float4*)&st2[gg][e] = *(const float4*)(T + (size_t)(bBase + gg) * MEM + 8 + e);
        }
        for (int m = tid * 4; m < NG * 32; m += 1024) {
            int gg = m >> 5, e = m & 31;
            *(float4*)&st3[gg][e] = *(const float4*)(T + (size_t)(bBase + gg) * MEM + 72 + s * 32 + e);
        }
        __syncthreads();

        if (tid < 64) {
            int i = tid >> 3, k = tid & 7;
            float p1acc = 0.f, p2acc = 0.f;
            for (int gg = 0; gg < NG; gg++) {
                sp2[gg][tid] = p2acc;
                if (k == 0) sp1[gg][i] = p1acc;
                if (s == 0) {
                    size_t prow = (size_t)(bBase + gg) * MEM;
                    P[prow + 8 + tid] = p2acc;
                    if (k == 0) P[prow + i] = p1acc;
                }
                p2acc += st2[gg][tid] + p1acc * st1[gg][k];
                p1acc += st1[gg][i];
            }
        }
        __syncthreads();
        if (tid < 32) {
            int ijk = s * 32 + tid;
            int i = ijk >> 6, jk2 = ijk & 63, ij = ijk >> 3, k = ijk & 7;
            float acc3 = 0.f;
            for (int gg = 0; gg < NG; gg++) {
                sp3[gg][tid] = acc3;
                P[(size_t)(bBase + gg) * MEM + 72 + ijk] = acc3;
                acc3 += st3[gg][tid] + sp1[gg][i] * st2[gg][jk2] + sp2[gg][ij] * st1[gg][k];
            }
        }
        __syncthreads();
        {
            const int i  = s >> 1;
            const int ij = (s << 2) + (tid >> 6);
            const int kl = tid & 63, l = tid & 7, p3 = tid >> 3;
            float acc4 = 0.f;
            size_t prowBase = (size_t)bBase * MEM + 584 + m4idx;
#pragma unroll
            for (int gg = 0; gg < NG; gg++) {
                P[prowBase + (size_t)gg * MEM] = acc4;
                acc4 += rL4[gg] + sp1[gg][i] * rL3[gg] + sp2[gg][ij] * st2[gg][kl] + sp3[gg][p3] * st1[gg][l];
            }
        }
    }

    grid_barrier(bar, bar + 1);

    // ---------------- phase 3: apply prefix + log + pool (snapshots from LDS) ---
    {
        const float* Prow = P + (size_t)bid * MEM;
        const float a1  = Prow[i1],  a2  = Prow[8 + row1], a3  = Prow[72 + tid];
        const float c1_ = Prow[i2],  c2_ = Prow[8 + row2], c3_ = Prow[72 + 256 + tid];
        float4 pa0 = *(const float4*)(Prow + 584 + tid * 8);
        float4 pa1 = *(const float4*)(Prow + 584 + tid * 8 + 4);
        float4 pb0 = *(const float4*)(Prow + 584 + (tid + 256) * 8);
        float4 pb1 = *(const float4*)(Prow + 584 + (tid + 256) * 8 + 4);
        float pP4a[8] = {pa0.x, pa0.y, pa0.z, pa0.w, pa1.x, pa1.y, pa1.z, pa1.w};
        float pP4b[8] = {pb0.x, pb0.y, pb0.z, pb0.w, pb1.x, pb1.y, pb1.z, pb1.w};
        const float p2v = (tid < 64) ? Prow[8 + tid] : 0.f;
        const float p1v = (tid < 8) ? Prow[tid] : 0.f;
        const float p2i = Prow[tid >> 3];

        float pool4a[8], pool4b[8];
#pragma unroll
        for (int l = 0; l < 8; l++) { pool4a[l] = 0.f; pool4b[l] = 0.f; }
        float pool3a = 0.f, pool3b = 0.f, pool2 = 0.f, pool1 = 0.f;

        for (int c = 0; c < 4; ++c) {
            const float* sAc = sSnap[c];
            const float* q3p = &sAc[P3OFF + jk * 9];
            const float* q2p = &sAc[8 + k1 * 8];
            float R4a[8], R4b[8];
#pragma unroll
            for (int l = 0; l < 8; l++) {
                float v3 = q3p[l], v2 = q2p[l], v1 = sAc[l];
                R4a[l] = pP4a[l] + sAc[P4OFF + tid * 9 + l]  + a1 * v3 + a2 * v2 + a3 * v1;
                R4b[l] = pP4b[l] + sAc[P4OFF + pos2 * 9 + l] + c1_ * v3 + c2_ * v2 + c3_ * v1;
            }
            float R3a = a3  + sAc[P3OFF + row1 * 9 + k1] + a1  * sAc[8 + jk] + a2  * sAc[k1];
            float R3b = c3_ + sAc[P3OFF + row2 * 9 + k1] + c1_ * sAc[8 + jk] + c2_ * sAc[k1];
            float R2v = 0.f, R1v = 0.f;
            if (tid < 64) R2v = p2v + sAc[8 + tid] + p2i * sAc[tid & 7];
            if (tid < 8)  R1v = p1v + sAc[tid];

            sR[P3OFF + row1 * 9 + k1] = R3a;
            sR[P3OFF + row2 * 9 + k1] = R3b;
            if (tid < 64) sR[8 + tid] = R2v;
            if (tid < 8)  sR[tid] = R1v;
            __syncthreads();

            float q23a = sR[i1] * sR[8 + jk] + sR[8 + row1] * sR[k1];
            float q23b = sR[i2] * sR[8 + jk] + sR[8 + row2] * sR[k1];
            {
                float s1ia = sR[i1], s1ib = sR[i2], s1j = sR[j1], s1k = sR[k1];
                float s2ija = sR[8 + row1], s2ijb = sR[8 + row2];
                float s2jk = sR[8 + jk];
                const float* r3p = &sR[P3OFF + jk * 9];
                const float* r2p = &sR[8 + k1 * 8];
#pragma unroll
                for (int l = 0; l < 8; l++) {
                    float s1l = sR[l];
                    float p22 = s1k * s1l;
                    float q23l = s1j * r2p[l] + s2jk * s1l;
                    float p24a = s1ia * r3p[l] + s2ija * r2p[l] + R3a * s1l;
                    float p24b = s1ib * r3p[l] + s2ijb * r2p[l] + R3b * s1l;
                    float p34a = s1ia * q23l + s2ija * p22;
                    float p34b = s1ib * q23l + s2ijb * p22;
                    float p44a = s1ia * s1j * p22;
                    float p44b = s1ib * s1j * p22;
                    pool4a[l] += R4a[l] - 0.5f * p24a + (1.f/3.f) * p34a - 0.25f * p44a;
                    pool4b[l] += R4b[l] - 0.5f * p24b + (1.f/3.f) * p34b - 0.25f * p44b;
                }
                pool3a += R3a - 0.5f * q23a + (1.f/3.f) * s1ia * s1j * s1k;
                pool3b += R3b - 0.5f * q23b + (1.f/3.f) * s1ib * s1j * s1k;
                if (tid < 64) pool2 += R2v - 0.5f * sR[tid >> 3] * sR[tid & 7];
                if (tid < 8)  pool1 += R1v;
            }
            __syncthreads();
        }

        float* pb = partial + (size_t)bid * MEM;
        *(float4*)(pb + 584 + tid * 8)     = make_float4(pool4a[0], pool4a[1], pool4a[2], pool4a[3]);
        *(float4*)(pb + 584 + tid * 8 + 4) = make_float4(pool4a[4], pool4a[5], pool4a[6], pool4a[7]);
        *(float4*)(pb + 584 + (tid + 256) * 8)     = make_float4(pool4b[0], pool4b[1], pool4b[2], pool4b[3]);
        *(float4*)(pb + 584 + (tid + 256) * 8 + 4) = make_float4(pool4b[4], pool4b[5], pool4b[6], pool4b[7]);
        pb[72 + tid] = pool3a;
        pb[72 + 256 + tid] = pool3b;
        if (tid < 64) pb[8 + tid] = pool2;
        if (tid < 8)  pb[tid] = pool1;
    }

    grid_barrier(bar, bar + 1);

    // ---------------- phase 4: reduce 32 group rows + gemv (blocks 0..146) ------
    if (bid < 147) {
        const int kc = bid;
        const int k0 = kc * 32;
        {
            int bb = tid >> 5, k = tid & 31;
            float sum = 0.f;
            if (k0 + k < MEM) {
                for (int gg = 0; gg < NG; gg++)
                    sum += partial[(size_t)(bb * NG + gg) * MEM + k0 + k];
            }
            spg[bb][k] = sum * (1.f / 128.f);
        }
        __syncthreads();
        float acc[8];
#pragma unroll
        for (int bb = 0; bb < 8; bb++) acc[bb] = 0.f;
        int kend = (k0 + 32 < MEM) ? 32 : (MEM - k0);
        for (int k = 0; k < kend; k++) {
            float wv = W1[(size_t)(k0 + k) * 256 + tid];
#pragma unroll
            for (int bb = 0; bb < 8; bb++) acc[bb] += spg[bb][k] * wv;
        }
#pragma unroll
        for (int bb = 0; bb < 8; bb++) hpart[(size_t)kc * 2048 + bb * 256 + tid] = acc[bb];
    }

    grid_barrier(bar, bar + 1);

    // ---------------- phase 5: reduce hpart + final MLP (blocks 0..7) -----------
    if (bid < 8) {
        float v = 0.f;
        for (int kc = 0; kc < 147; kc++) v += hpart[(size_t)kc * 2048 + bid * 256 + tid];
        v += b1[tid];
        v = fmaxf(v, 0.f) * W2[tid];
        sRed[tid] = v;
        __syncthreads();
        for (int s = 128; s > 0; s >>= 1) {
            if (tid < s) sRed[tid] += sRed[tid + s];
            __syncthreads();
        }
        if (tid == 0) outp[bid] = sRed[0] + b2[0];
    }
}

// ------------------------------------------------ launch
extern "C" void kernel_launch(void* const* d_in, const int* in_sizes, int n_in,
                              void* d_out, int out_size, void* d_ws, size_t ws_size,
                              hipStream_t stream) {
    const float* x  = (const float*)d_in[0];
    const float* W1 = (const float*)d_in[1];
    const float* b1 = (const float*)d_in[2];
    const float* W2 = (const float*)d_in[3];
    const float* b2 = (const float*)d_in[4];
    float* out = (float*)d_out;

    float* ws = (float*)d_ws;
    float* T       = ws;                            // 256*MEM (group totals, compact)
    float* P       = T + (size_t)256 * MEM;         // 256*MEM (exclusive group prefixes)
    float* partial = P + (size_t)256 * MEM;         // 256*MEM (per-group pooled rows)
    float* hpart   = partial + (size_t)256 * MEM;   // 147*2048 (gemv partials)
    size_t baroff = (size_t)256 * MEM * 3 + (size_t)147 * 2048;
    baroff = (baroff + 31) & ~(size_t)31;           // 128B-align barrier words
    unsigned* bar = (unsigned*)(ws + baroff);       // [cnt, gen]

    // workspace is poisoned each iteration: cnt MUST be zeroed (gen is generation-
    // tolerant and needs no init, but zero both). Stream-ordered, graph-capturable.
    hipMemsetAsync(bar, 0, 8, stream);
    fused_kernel<<<NBLK, 256, 0, stream>>>(x, W1, b1, W2, b2, out, T, P, partial, hpart, bar);
}

// Round 3
// 262.063 us; speedup vs baseline: 1.0877x; 1.0877x over previous
//
#include <hip/hip_runtime.h>

// BLAMem: truncated tensor-algebra (depth 4, C=8) log-signature memory.
// Round-10: single fused kernel (round-9 structure, phases bit-identical) with the
// grid barrier REPLACED. Round-9 evidence: kernel 225-230us at VALUBusy 3.6% => ~220us
// idle = 4 barriers x ~55us. Cause: 256 device-scope fetch_adds to ONE word serialize
// cross-XCD at ~200-250ns each. New barrier is contention-free: arrival is a release
// STORE to flags[bid] (256 distinct words, pipelined), detection is block 0's 256
// threads polling one flag each, publication is a single gen word. No atomic RMW
// anywhere. Carried lessons: NO atomics for reductions; LDS rows padded to stride 9;
// FP summation orders bit-identical to the verified round-0/1/2 kernels.

#define MEM   4680   // 8 + 64 + 512 + 4096 (unpadded global layout)
#define NG    32     // groups per batch
#define TLEN  2048
#define NBLK  256

// Padded LDS signature layout: L1 [0,8), L2 [8,72), L3 rows (i*8+j)*9+k at 72 (576),
// L4 rows ijk*9+l at 648 (4608). Total 5256 floats.
#define P3OFF 72
#define P4OFF 648
#define SIGSZ 5256

// Contention-free grid barrier (generation k = 1,2,3,...; flags/gen zeroed by the
// pre-launch memset). Arrival: leader release-stores k to flags[bid] (own word -> no
// RMW serialization). Detection: block 0, thread t polls flags[t]. Publication: gen.
// __syncthreads drains each wave's vmem ops before the leader's agent fence, so all
// of this block's global writes are device-visible before flags[bid]=k (same
// ordering structure round-9 validated functionally).
__device__ __forceinline__ void grid_barrier(unsigned* flags, unsigned* gen, unsigned k) {
    __syncthreads();
    const int tid = threadIdx.x;
    if (tid == 0) {
        __threadfence();
        __hip_atomic_store(&flags[blockIdx.x], k, __ATOMIC_RELEASE, __HIP_MEMORY_SCOPE_AGENT);
    }
    if (blockIdx.x == 0) {
        while (__hip_atomic_load(&flags[tid], __ATOMIC_RELAXED, __HIP_MEMORY_SCOPE_AGENT) < k)
            __builtin_amdgcn_s_sleep(8);
        __threadfence();      // acquire side of the flag handshake (per polling thread)
        __syncthreads();
        if (tid == 0) {
            __hip_atomic_store(gen, k, __ATOMIC_RELEASE, __HIP_MEMORY_SCOPE_AGENT);
        }
    }
    if (tid == 0) {
        while (__hip_atomic_load(gen, __ATOMIC_ACQUIRE, __HIP_MEMORY_SCOPE_AGENT) < k)
            __builtin_amdgcn_s_sleep(8);
        __threadfence();
    }
    __syncthreads();
}

__global__ __launch_bounds__(256) void fused_kernel(
    const float* __restrict__ x,  const float* __restrict__ W1,
    const float* __restrict__ b1, const float* __restrict__ W2,
    const float* __restrict__ b2, float* __restrict__ outp,
    float* __restrict__ T, float* __restrict__ P,
    float* __restrict__ partial, float* __restrict__ hpart,
    unsigned* __restrict__ barflags, unsigned* __restrict__ bargen)
{
    const int bid = blockIdx.x;
    const int tid = threadIdx.x;
    const int b = bid >> 5, g = bid & 31;

    // Persistent across phases (block owns one CU): 4 padded chunk snapshots.
    __shared__ __attribute__((aligned(16))) float sSnap[4][SIGSZ];   // 84.1 KB
    __shared__ __attribute__((aligned(16))) float sInc[512];
    __shared__ __attribute__((aligned(16))) float U[648];   // loc3 576 | loc2 64 | loc1 8
    __shared__ __attribute__((aligned(16))) float sR[648];
    // scan phase
    __shared__ float st1[NG][8];
    __shared__ float st2[NG][64];
    __shared__ float st3[NG][32];
    __shared__ float sp1[NG][8];
    __shared__ float sp2[NG][64];
    __shared__ float sp3[NG][32];
    // gemv / final
    __shared__ float spg[8][32];
    __shared__ float sRed[256];

    const int i1 = tid >> 6, j1 = (tid >> 3) & 7, k1 = tid & 7;
    const int row1 = tid >> 3, row2 = row1 + 32;
    const int jk = tid & 63;
    const int pos2 = tid + 256, i2 = pos2 >> 6;

    float* loc3 = U;
    float* loc2 = U + 576;
    float* loc1 = U + 640;

    // ---------------- phase 1: per-group Chen fold, snapshots kept in LDS -------
    for (int e = tid; e < 512; e += 256) {
        int s = e >> 3, c = e & 7;
        int t = g * 64 + s;
        float v;
        if (c < 7) {
            float cur  = x[(b * TLEN + t) * 7 + c];
            float prev = (t > 0) ? x[(b * TLEN + t - 1) * 7 + c] : 0.f;
            v = cur - prev;
        } else v = (t > 0) ? (1.f / 2047.f) : 0.f;
        sInc[e] = v;
    }
    __syncthreads();

    for (int c = 0; c < 4; ++c) {
        const float* dch = &sInc[c * 128];
        float p1a = 0.f, l2a = 0.f, l3a = 0.f, p1b = 0.f, l2b = 0.f, l3b = 0.f;
        float Sa[8], Sb[8];
#pragma unroll
        for (int l = 0; l < 8; l++) { Sa[l] = 0.f; Sb[l] = 0.f; }
#pragma unroll
        for (int t = 0; t < 16; t++) {
            const float* dr = dch + t * 8;
            float di1 = dr[i1], di2 = dr[i2], dj = dr[j1], dk = dr[k1];
            float ga = l3a + dk * (l2a * 0.5f + dj * (p1a * (1.f/6.f) + di1 * (1.f/24.f)));
            float gb = l3b + dk * (l2b * 0.5f + dj * (p1b * (1.f/6.f) + di2 * (1.f/24.f)));
#pragma unroll
            for (int l = 0; l < 8; l++) { float dv = dr[l]; Sa[l] += ga * dv; Sb[l] += gb * dv; }
            l3a += dk * (l2a + dj * (p1a * 0.5f + di1 * (1.f/6.f)));
            l3b += dk * (l2b + dj * (p1b * 0.5f + di2 * (1.f/6.f)));
            l2a += (p1a + di1 * 0.5f) * dj;
            l2b += (p1b + di2 * 0.5f) * dj;
            p1a += di1; p1b += di2;
        }
        loc3[row1 * 9 + k1] = l3a;
        loc3[row2 * 9 + k1] = l3b;
        if (k1 == 0) { loc2[row1] = l2a; loc2[row2] = l2b; }
        if (jk == 0) { loc1[i1] = p1a; loc1[i2] = p1b; }
        __syncthreads();

        float* dst = sSnap[c];
        const float* l3p = &loc3[jk * 9];
        const float* l2p = &loc2[k1 * 8];
        if (c == 0) {
            // prev == 0: snapshot = chunk-local sig (bit-identical to merging with 0)
#pragma unroll
            for (int l = 0; l < 8; l++) { dst[P4OFF + tid * 9 + l] = Sa[l]; dst[P4OFF + pos2 * 9 + l] = Sb[l]; }
            dst[P3OFF + row1 * 9 + k1] = l3a;
            dst[P3OFF + row2 * 9 + k1] = l3b;
            if (tid < 64) dst[8 + tid] = loc2[tid];
            if (tid < 8)  dst[tid] = loc1[tid];
        } else {
            const float* prv = sSnap[c - 1];
            float a1 = prv[i1], a2 = prv[8 + row1], a3 = prv[P3OFF + row1 * 9 + k1];
            float c1_ = prv[i2], c2_ = prv[8 + row2], c3_ = prv[P3OFF + row2 * 9 + k1];
#pragma unroll
            for (int l = 0; l < 8; l++) {
                float v3 = l3p[l], v2 = l2p[l], v1 = loc1[l];
                dst[P4OFF + tid * 9 + l]  = prv[P4OFF + tid * 9 + l]  + Sa[l] + a1 * v3 + a2 * v2 + a3 * v1;
                dst[P4OFF + pos2 * 9 + l] = prv[P4OFF + pos2 * 9 + l] + Sb[l] + c1_ * v3 + c2_ * v2 + c3_ * v1;
            }
            dst[P3OFF + row1 * 9 + k1] = a3 + l3a + a1 * loc2[jk] + a2 * loc1[k1];
            dst[P3OFF + row2 * 9 + k1] = c3_ + l3b + c1_ * loc2[jk] + c2_ * loc1[k1];
            if (tid < 64) dst[8 + tid] = prv[8 + tid] + loc2[tid] + prv[tid >> 3] * loc1[tid & 7];
            if (tid < 8)  dst[tid] = prv[tid] + loc1[tid];
        }
        __syncthreads();
    }

    // write group totals (snapshot 3) compact for the scan
    {
        const float* s3 = sSnap[3];
        float* Tr = T + (size_t)bid * MEM;
        for (int m4 = tid * 4; m4 < MEM; m4 += 1024) {
            float4 v;
            if (m4 < 72) {
                v = make_float4(s3[m4], s3[m4 + 1], s3[m4 + 2], s3[m4 + 3]);
            } else if (m4 < 584) {
                int e = m4 - 72; const float* p0 = &s3[P3OFF + (e >> 3) * 9 + (e & 7)];
                v = make_float4(p0[0], p0[1], p0[2], p0[3]);
            } else {
                int e = m4 - 584; const float* p0 = &s3[P4OFF + (e >> 3) * 9 + (e & 7)];
                v = make_float4(p0[0], p0[1], p0[2], p0[3]);
            }
            *(float4*)(Tr + m4) = v;
        }
    }

    grid_barrier(barflags, bargen, 1u);

    // ---------------- phase 2: cross-group cascade scan (blocks 0..127) ---------
    if (bid < 128) {
        const int b2 = bid >> 4, s = bid & 15;
        const int bBase = b2 * NG;
        const int jkl   = ((s & 1) << 8) | tid;
        const int m4idx = s * 256 + tid;

        float rL4[NG], rL3[NG];
#pragma unroll
        for (int gg = 0; gg < NG; gg++) {
            const float* Trow = T + (size_t)(bBase + gg) * MEM;
            rL4[gg] = Trow[584 + m4idx];
            rL3[gg] = Trow[72 + jkl];
        }
        {
            int gg = tid >> 3, i = tid & 7;
            st1[gg][i] = T[(size_t)(bBase + gg) * MEM + i];
        }
        for (int m = tid * 4; m < NG * 64; m += 1024) {
            int gg = m >> 6, e = m & 63;
            *(float4*)&st2[gg][e] = *(const float4*)(T + (size_t)(bBase + gg) * MEM + 8 + e);
        }
        for (int m = tid * 4; m < NG * 32; m += 1024) {
            int gg = m >> 5, e = m & 31;
            *(float4*)&st3[gg][e] = *(const float4*)(T + (size_t)(bBase + gg) * MEM + 72 + s * 32 + e);
        }
        __syncthreads();

        if (tid < 64) {
            int i = tid >> 3, k = tid & 7;
            float p1acc = 0.f, p2acc = 0.f;
            for (int gg = 0; gg < NG; gg++) {
                sp2[gg][tid] = p2acc;
                if (k == 0) sp1[gg][i] = p1acc;
                if (s == 0) {
                    size_t prow = (size_t)(bBase + gg) * MEM;
                    P[prow + 8 + tid] = p2acc;
                    if (k == 0) P[prow + i] = p1acc;
                }
                p2acc += st2[gg][tid] + p1acc * st1[gg][k];
                p1acc += st1[gg][i];
            }
        }
        __syncthreads();
        if (tid < 32) {
            int ijk = s * 32 + tid;
            int i = ijk >> 6, jk2 = ijk & 63, ij = ijk >> 3, k = ijk & 7;
            float acc3 = 0.f;
            for (int gg = 0; gg < NG; gg++) {
                sp3[gg][tid] = acc3;
                P[(size_t)(bBase + gg) * MEM + 72 + ijk] = acc3;
                acc3 += st3[gg][tid] + sp1[gg][i] * st2[gg][jk2] + sp2[gg][ij] * st1[gg][k];
            }
        }
        __syncthreads();
        {
            const int i  = s >> 1;
            const int ij = (s << 2) + (tid >> 6);
            const int kl = tid & 63, l = tid & 7, p3 = tid >> 3;
            float acc4 = 0.f;
            size_t prowBase = (size_t)bBase * MEM + 584 + m4idx;
#pragma unroll
            for (int gg = 0; gg < NG; gg++) {
                P[prowBase + (size_t)gg * MEM] = acc4;
                acc4 += rL4[gg] + sp1[gg][i] * rL3[gg] + sp2[gg][ij] * st2[gg][kl] + sp3[gg][p3] * st1[gg][l];
            }
        }
    }

    grid_barrier(barflags, bargen, 2u);

    // ---------------- phase 3: apply prefix + log + pool (snapshots from LDS) ---
    {
        const float* Prow = P + (size_t)bid * MEM;
        const float a1  = Prow[i1],  a2  = Prow[8 + row1], a3  = Prow[72 + tid];
        const float c1_ = Prow[i2],  c2_ = Prow[8 + row2], c3_ = Prow[72 + 256 + tid];
        float4 pa0 = *(const float4*)(Prow + 584 + tid * 8);
        float4 pa1 = *(const float4*)(Prow + 584 + tid * 8 + 4);
        float4 pb0 = *(const float4*)(Prow + 584 + (tid + 256) * 8);
        float4 pb1 = *(const float4*)(Prow + 584 + (tid + 256) * 8 + 4);
        float pP4a[8] = {pa0.x, pa0.y, pa0.z, pa0.w, pa1.x, pa1.y, pa1.z, pa1.w};
        float pP4b[8] = {pb0.x, pb0.y, pb0.z, pb0.w, pb1.x, pb1.y, pb1.z, pb1.w};
        const float p2v = (tid < 64) ? Prow[8 + tid] : 0.f;
        const float p1v = (tid < 8) ? Prow[tid] : 0.f;
        const float p2i = Prow[tid >> 3];

        float pool4a[8], pool4b[8];
#pragma unroll
        for (int l = 0; l < 8; l++) { pool4a[l] = 0.f; pool4b[l] = 0.f; }
        float pool3a = 0.f, pool3b = 0.f, pool2 = 0.f, pool1 = 0.f;

        for (int c = 0; c < 4; ++c) {
            const float* sAc = sSnap[c];
            const float* q3p = &sAc[P3OFF + jk * 9];
            const float* q2p = &sAc[8 + k1 * 8];
            float R4a[8], R4b[8];
#pragma unroll
            for (int l = 0; l < 8; l++) {
                float v3 = q3p[l], v2 = q2p[l], v1 = sAc[l];
                R4a[l] = pP4a[l] + sAc[P4OFF + tid * 9 + l]  + a1 * v3 + a2 * v2 + a3 * v1;
                R4b[l] = pP4b[l] + sAc[P4OFF + pos2 * 9 + l] + c1_ * v3 + c2_ * v2 + c3_ * v1;
            }
            float R3a = a3  + sAc[P3OFF + row1 * 9 + k1] + a1  * sAc[8 + jk] + a2  * sAc[k1];
            float R3b = c3_ + sAc[P3OFF + row2 * 9 + k1] + c1_ * sAc[8 + jk] + c2_ * sAc[k1];
            float R2v = 0.f, R1v = 0.f;
            if (tid < 64) R2v = p2v + sAc[8 + tid] + p2i * sAc[tid & 7];
            if (tid < 8)  R1v = p1v + sAc[tid];

            sR[P3OFF + row1 * 9 + k1] = R3a;
            sR[P3OFF + row2 * 9 + k1] = R3b;
            if (tid < 64) sR[8 + tid] = R2v;
            if (tid < 8)  sR[tid] = R1v;
            __syncthreads();

            float q23a = sR[i1] * sR[8 + jk] + sR[8 + row1] * sR[k1];
            float q23b = sR[i2] * sR[8 + jk] + sR[8 + row2] * sR[k1];
            {
                float s1ia = sR[i1], s1ib = sR[i2], s1j = sR[j1], s1k = sR[k1];
                float s2ija = sR[8 + row1], s2ijb = sR[8 + row2];
                float s2jk = sR[8 + jk];
                const float* r3p = &sR[P3OFF + jk * 9];
                const float* r2p = &sR[8 + k1 * 8];
#pragma unroll
                for (int l = 0; l < 8; l++) {
                    float s1l = sR[l];
                    float p22 = s1k * s1l;
                    float q23l = s1j * r2p[l] + s2jk * s1l;
                    float p24a = s1ia * r3p[l] + s2ija * r2p[l] + R3a * s1l;
                    float p24b = s1ib * r3p[l] + s2ijb * r2p[l] + R3b * s1l;
                    float p34a = s1ia * q23l + s2ija * p22;
                    float p34b = s1ib * q23l + s2ijb * p22;
                    float p44a = s1ia * s1j * p22;
                    float p44b = s1ib * s1j * p22;
                    pool4a[l] += R4a[l] - 0.5f * p24a + (1.f/3.f) * p34a - 0.25f * p44a;
                    pool4b[l] += R4b[l] - 0.5f * p24b + (1.f/3.f) * p34b - 0.25f * p44b;
                }
                pool3a += R3a - 0.5f * q23a + (1.f/3.f) * s1ia * s1j * s1k;
                pool3b += R3b - 0.5f * q23b + (1.f/3.f) * s1ib * s1j * s1k;
                if (tid < 64) pool2 += R2v - 0.5f * sR[tid >> 3] * sR[tid & 7];
                if (tid < 8)  pool1 += R1v;
            }
            __syncthreads();
        }

        float* pb = partial + (size_t)bid * MEM;
        *(float4*)(pb + 584 + tid * 8)     = make_float4(pool4a[0], pool4a[1], pool4a[2], pool4a[3]);
        *(float4*)(pb + 584 + tid * 8 + 4) = make_float4(pool4a[4], pool4a[5], pool4a[6], pool4a[7]);
        *(float4*)(pb + 584 + (tid + 256) * 8)     = make_float4(pool4b[0], pool4b[1], pool4b[2], pool4b[3]);
        *(float4*)(pb + 584 + (tid + 256) * 8 + 4) = make_float4(pool4b[4], pool4b[5], pool4b[6], pool4b[7]);
        pb[72 + tid] = pool3a;
        pb[72 + 256 + tid] = pool3b;
        if (tid < 64) pb[8 + tid] = pool2;
        if (tid < 8)  pb[tid] = pool1;
    }

    grid_barrier(barflags, bargen, 3u);

    // ---------------- phase 4: reduce 32 group rows + gemv (blocks 0..146) ------
    if (bid < 147) {
        const int kc = bid;
        const int k0 = kc * 32;
        {
            int bb = tid >> 5, k = tid & 31;
            float sum = 0.f;
            if (k0 + k < MEM) {
                for (int gg = 0; gg < NG; gg++)
                    sum += partial[(size_t)(bb * NG + gg) * MEM + k0 + k];
            }
            spg[bb][k] = sum * (1.f / 128.f);
        }
        __syncthreads();
        float acc[8];
#pragma unroll
        for (int bb = 0; bb < 8; bb++) acc[bb] = 0.f;
        int kend = (k0 + 32 < MEM) ? 32 : (MEM - k0);
        for (int k = 0; k < kend; k++) {
            float wv = W1[(size_t)(k0 + k) * 256 + tid];
#pragma unroll
            for (int bb = 0; bb < 8; bb++) acc[bb] += spg[bb][k] * wv;
        }
#pragma unroll
        for (int bb = 0; bb < 8; bb++) hpart[(size_t)kc * 2048 + bb * 256 + tid] = acc[bb];
    }

    grid_barrier(barflags, bargen, 4u);

    // ---------------- phase 5: reduce hpart + final MLP (blocks 0..7) -----------
    if (bid < 8) {
        float v = 0.f;
        for (int kc = 0; kc < 147; kc++) v += hpart[(size_t)kc * 2048 + bid * 256 + tid];
        v += b1[tid];
        v = fmaxf(v, 0.f) * W2[tid];
        sRed[tid] = v;
        __syncthreads();
        for (int s = 128; s > 0; s >>= 1) {
            if (tid < s) sRed[tid] += sRed[tid + s];
            __syncthreads();
        }
        if (tid == 0) outp[bid] = sRed[0] + b2[0];
    }
}

// ------------------------------------------------ launch
extern "C" void kernel_launch(void* const* d_in, const int* in_sizes, int n_in,
                              void* d_out, int out_size, void* d_ws, size_t ws_size,
                              hipStream_t stream) {
    const float* x  = (const float*)d_in[0];
    const float* W1 = (const float*)d_in[1];
    const float* b1 = (const float*)d_in[2];
    const float* W2 = (const float*)d_in[3];
    const float* b2 = (const float*)d_in[4];
    float* out = (float*)d_out;

    float* ws = (float*)d_ws;
    float* T       = ws;                            // 256*MEM (group totals, compact)
    float* P       = T + (size_t)256 * MEM;         // 256*MEM (exclusive group prefixes)
    float* partial = P + (size_t)256 * MEM;         // 256*MEM (per-group pooled rows)
    float* hpart   = partial + (size_t)256 * MEM;   // 147*2048 (gemv partials)
    size_t baroff = (size_t)256 * MEM * 3 + (size_t)147 * 2048;
    baroff = (baroff + 31) & ~(size_t)31;           // 128B-align barrier region
    unsigned* barflags = (unsigned*)(ws + baroff);  // flags[256], 1KB (8 x 128B lines)
    unsigned* bargen   = barflags + 288;            // own 128B line (byte offset 1152)

    // workspace is poisoned each iteration: flags and gen MUST be zeroed.
    // Stream-ordered, graph-capturable (no sync/alloc here).
    hipMemsetAsync(barflags, 0, 1280, stream);
    fused_kernel<<<NBLK, 256, 0, stream>>>(x, W1, b1, W2, b2, out, T, P, partial, hpart,
                                           barflags, bargen);
}